// Round 2
// baseline (781.562 us; speedup 1.0000x reference)
//
#include <hip/hip_runtime.h>

// RPDC depthwise sparse-5x5 (pixel-difference) conv, float4 + shuffle version.
// x: (16,256,128,128) fp32, weight: (256,1,3,3) fp32, out same shape.
//
// out(h,w) = t0*(A[w-2]-B[w-1]) + t1*(A[w]-B[w]) + t2*(A[w+2]-B[w+1])
//          + t3*(C[w-2]-C[w-1]) + t4*(C[w+2]-C[w+1])
//          + t5*(E[w-2]-D[w-1]) + t6*(E[w]-D[w]) + t7*(E[w+2]-D[w+1])
// A..E = rows h-2..h+2 (zero-pad), tj = weight[c] flat index 1+j.
//
// R2 change vs R1: 1x global_load_dwordx4 per row per thread (was 5x dword),
// halo columns via __shfl from neighbor lanes (LDS pipe, idle otherwise).
// 4 cols/thread, 32 threads/row, H split in 2 chunks of 64 rows for occupancy.

#define HH 128
#define WW 128
#define CH 64   // rows per chunk (2 chunks per plane; halo re-read = 4/64 = 6%)

__global__ __launch_bounds__(256, 6) void rpdc_kernel(
    const float* __restrict__ x, const float* __restrict__ wt,
    float* __restrict__ out, int C)
{
    const int tid  = threadIdx.x;
    const int lane = tid & 31;              // 32 threads per image row
    const int unit = tid >> 5;              // 8 units per block
    const int plane = blockIdx.x * 4 + (unit >> 1);  // wave = 1 plane (2 halves)
    const int half  = unit & 1;
    const int h0    = half * CH;
    const int c     = plane & (C - 1);      // C = 256 (pow2)

    const float* wp = wt + (size_t)c * 9;
    const float t0 = wp[1], t1 = wp[2], t2 = wp[3], t3 = wp[4],
                t4 = wp[5], t5 = wp[6], t6 = wp[7], t7 = wp[8];

    const float* xp = x   + (size_t)plane * (HH * WW) + lane * 4;
    float*       op = out + (size_t)plane * (HH * WW) + (size_t)h0 * WW + lane * 4;

    const float eL = (lane == 0)  ? 0.f : 1.f;   // cols -2,-1 are zero-pad
    const float eR = (lane == 31) ? 0.f : 1.f;   // cols 128,129 are zero-pad

    // 8-wide column window per row: [w-2, w-1, w, w+1, w+2, w+3, w+4, w+5]
    // (own float4 at idx 2..5; halo from lane-1 at 0..1, lane+1 at 6..7)
    float A[8], B[8], Cw[8], D[8], E[8];

#define LOADROW(r, W8) do {                                             \
    const int _rc = (r) < 0 ? 0 : ((r) > HH - 1 ? HH - 1 : (r));        \
    const float _m = ((r) >= 0 && (r) < HH) ? 1.f : 0.f;                \
    float4 _v = *(const float4*)(xp + (size_t)_rc * WW);                \
    _v.x *= _m; _v.y *= _m; _v.z *= _m; _v.w *= _m;                     \
    (W8)[2] = _v.x; (W8)[3] = _v.y; (W8)[4] = _v.z; (W8)[5] = _v.w;     \
    (W8)[0] = __shfl(_v.z, lane - 1, 32) * eL;                          \
    (W8)[1] = __shfl(_v.w, lane - 1, 32) * eL;                          \
    (W8)[6] = __shfl(_v.x, lane + 1, 32) * eR;                          \
    (W8)[7] = __shfl(_v.y, lane + 1, 32) * eR;                          \
  } while (0)

    // prologue: rows h0-2 .. h0+2 (zero-masked outside [0,128))
    LOADROW(h0 - 2, A);
    LOADROW(h0 - 1, B);
    LOADROW(h0,     Cw);
    LOADROW(h0 + 1, D);
    LOADROW(h0 + 2, E);

#pragma unroll 4
    for (int i = 0; i < CH; ++i) {
        float res[4];
#pragma unroll
        for (int j = 0; j < 4; ++j) {
            // window idx: w-2 -> j, w-1 -> j+1, w -> j+2, w+1 -> j+3, w+2 -> j+4
            float r = t0 * (A[j]     - B[j + 1]);
            r += t1 * (A[j + 2] - B[j + 2]);
            r += t2 * (A[j + 4] - B[j + 3]);
            r += t3 * (Cw[j]    - Cw[j + 1]);
            r += t4 * (Cw[j + 4] - Cw[j + 3]);
            r += t5 * (E[j]     - D[j + 1]);
            r += t6 * (E[j + 2] - D[j + 2]);
            r += t7 * (E[j + 4] - D[j + 3]);
            res[j] = r;
        }
        float4 o = { res[0], res[1], res[2], res[3] };
        *(float4*)(op + (size_t)i * WW) = o;

#pragma unroll
        for (int k = 0; k < 8; ++k) { A[k] = B[k]; B[k] = Cw[k]; Cw[k] = D[k]; D[k] = E[k]; }

        LOADROW(h0 + i + 3, E);   // branchless: clamped row + zero mask
    }
#undef LOADROW
}

extern "C" void kernel_launch(void* const* d_in, const int* in_sizes, int n_in,
                              void* d_out, int out_size, void* d_ws, size_t ws_size,
                              hipStream_t stream) {
    const float* x  = (const float*)d_in[0];
    const float* wt = (const float*)d_in[1];
    float* out = (float*)d_out;

    const int C = in_sizes[1] / 9;                  // 256
    const int planes = in_sizes[0] / (HH * WW);     // 4096

    dim3 grid(planes / 4);    // 4 planes x 2 half-chunks = 8 units per block
    dim3 block(256);
    rpdc_kernel<<<grid, block, 0, stream>>>(x, wt, out, C);
}